// Round 5
// baseline (372.438 us; speedup 1.0000x reference)
//
#include <hip/hip_runtime.h>
#include <hip/hip_bf16.h>
#include <cstdint>

// Problem constants
#define B_   8
#define L_   2048
#define E_   1024
#define H_   16
#define D_   64
#define M_   (B_ * L_)
#define EPS_ 1e-6f
#define PI2_ 1.57079632679f

typedef __bf16 bf16;
typedef __bf16 bf16x8 __attribute__((ext_vector_type(8)));
typedef __bf16 bf16x4 __attribute__((ext_vector_type(4)));
typedef float  floatx4 __attribute__((ext_vector_type(4)));
typedef unsigned int uintx4 __attribute__((ext_vector_type(4)));

__device__ inline void async_cp16(const void* g, void* l) {
  __builtin_amdgcn_global_load_lds(
      (__attribute__((address_space(1))) void*)const_cast<void*>(g),
      (__attribute__((address_space(3))) void*)l,
      16, 0, 0);
}

__device__ inline void nt_store16(bf16x8 v, bf16* p) {
  __builtin_nontemporal_store(*(const uintx4*)&v, (uintx4*)p);
}
__device__ inline float ld_bf16_nt(const bf16* p) {
  unsigned short s = __builtin_nontemporal_load((const unsigned short*)p);
  unsigned int ui = (unsigned int)s << 16;
  return __uint_as_float(ui);
}

// ---------------------------------------------------------------------------
// K1: fp32 -> bf16 convert (query -> Xbf).  nt loads (query read once).
// ---------------------------------------------------------------------------
__global__ __launch_bounds__(256) void k_convert_x(const float* __restrict__ x,
                                                   bf16* __restrict__ o) {
  size_t i = ((size_t)blockIdx.x * 256 + threadIdx.x) * 8;
  floatx4 a = __builtin_nontemporal_load(reinterpret_cast<const floatx4*>(x + i));
  floatx4 b = __builtin_nontemporal_load(reinterpret_cast<const floatx4*>(x + i + 4));
  bf16x8 r;
  r[0] = (bf16)a[0]; r[1] = (bf16)a[1]; r[2] = (bf16)a[2]; r[3] = (bf16)a[3];
  r[4] = (bf16)b[0]; r[5] = (bf16)b[1]; r[6] = (bf16)b[2]; r[7] = (bf16)b[3];
  *(bf16x8*)(o + i) = r;
}

// ---------------------------------------------------------------------------
// K2: transpose 4 weight matrices (E x E fp32 (in,out)) -> bf16 (out,in)
// ---------------------------------------------------------------------------
struct TArgs { const float* src[4]; bf16* dst[4]; };

__global__ __launch_bounds__(256) void k_transpose_w(TArgs t) {
  __shared__ float tile[32][33];
  const float* src = t.src[blockIdx.z];
  bf16* dst = t.dst[blockIdx.z];
  int bx = blockIdx.x, by = blockIdx.y;
  int x = threadIdx.x, y = threadIdx.y;  // (32, 8)
#pragma unroll
  for (int i = 0; i < 4; i++) {
    int r = by * 32 + y + i * 8;
    tile[y + i * 8][x] = src[(size_t)r * E_ + bx * 32 + x];
  }
  __syncthreads();
#pragma unroll
  for (int i = 0; i < 4; i++) {
    int r = bx * 32 + y + i * 8;
    dst[(size_t)r * E_ + by * 32 + x] = (bf16)tile[x][y + i * 8];
  }
}

// ---------------------------------------------------------------------------
// 256x256x64 8-phase GEMM core (T1+T2+T3/T4+T5).  8 waves = 2(M) x 4(N);
// per-wave output 128x64; NT=16 K-tiles; LDS st-swizzle via pre-swizzled
// global source (linear global_load_lds dest) + swizzled ds_read; counted
// vmcnt(4) once per tile, never 0 in steady state.
// ---------------------------------------------------------------------------
#define BAR()   asm volatile("s_barrier" ::: "memory")
#define LGKM0() asm volatile("s_waitcnt lgkmcnt(0)" ::: "memory")
#define VMW4()  asm volatile("s_waitcnt vmcnt(4)" ::: "memory")
#define VMW0()  asm volatile("s_waitcnt vmcnt(0)" ::: "memory")
#define MFMA_   __builtin_amdgcn_mfma_f32_16x16x32_bf16

#define GEMM_TILE(t_, c_) {                                                    \
    const int t = (t_); const int c = (c_);                                    \
    bf16x8 a0[4][2], a1[4][2], b0[2][2], b1[2][2];                             \
    /* phase 0 */                                                              \
    _Pragma("unroll") for (int i = 0; i < 4; i++) {                            \
      a0[i][0] = RDA(c, 0, i); a0[i][1] = RDA(c, 1, i); }                      \
    _Pragma("unroll") for (int j = 0; j < 2; j++) {                            \
      b0[j][0] = RDB(c, 0, j); b0[j][1] = RDB(c, 1, j); }                      \
    if (t + 1 < 16) STAGE(c ^ 1, 0, t + 1, 0);                                 \
    BAR(); LGKM0();                                                            \
    __builtin_amdgcn_s_setprio(1);                                             \
    _Pragma("unroll") for (int i = 0; i < 4; i++)                              \
      _Pragma("unroll") for (int j = 0; j < 2; j++) {                          \
        acc[i][j] = MFMA_(a0[i][0], b0[j][0], acc[i][j], 0, 0, 0);             \
        acc[i][j] = MFMA_(a0[i][1], b0[j][1], acc[i][j], 0, 0, 0); }           \
    __builtin_amdgcn_s_setprio(0);                                             \
    BAR();                                                                     \
    /* phase 1 */                                                              \
    _Pragma("unroll") for (int j = 0; j < 2; j++) {                            \
      b1[j][0] = RDB(c, 0, j + 2); b1[j][1] = RDB(c, 1, j + 2); }              \
    if (t + 1 < 16) STAGE(c ^ 1, 0, t + 1, 1);                                 \
    BAR(); LGKM0();                                                            \
    __builtin_amdgcn_s_setprio(1);                                             \
    _Pragma("unroll") for (int i = 0; i < 4; i++)                              \
      _Pragma("unroll") for (int j = 0; j < 2; j++) {                          \
        acc[i][j + 2] = MFMA_(a0[i][0], b1[j][0], acc[i][j + 2], 0, 0, 0);     \
        acc[i][j + 2] = MFMA_(a0[i][1], b1[j][1], acc[i][j + 2], 0, 0, 0); }   \
    __builtin_amdgcn_s_setprio(0);                                             \
    BAR();                                                                     \
    /* phase 2 */                                                              \
    _Pragma("unroll") for (int i = 0; i < 4; i++) {                            \
      a1[i][0] = RDA(c, 0, i + 4); a1[i][1] = RDA(c, 1, i + 4); }              \
    if (t + 2 < 16) STAGE(c, 1, t + 2, 0);                                     \
    BAR(); LGKM0();                                                            \
    __builtin_amdgcn_s_setprio(1);                                             \
    _Pragma("unroll") for (int i = 0; i < 4; i++)                              \
      _Pragma("unroll") for (int j = 0; j < 2; j++) {                          \
        acc[i + 4][j + 2] = MFMA_(a1[i][0], b1[j][0], acc[i + 4][j + 2], 0, 0, 0); \
        acc[i + 4][j + 2] = MFMA_(a1[i][1], b1[j][1], acc[i + 4][j + 2], 0, 0, 0); } \
    __builtin_amdgcn_s_setprio(0);                                             \
    BAR();                                                                     \
    /* phase 3 */                                                              \
    if (t < 14) { STAGE(c, 1, t + 2, 1); VMW4(); } else { VMW0(); }            \
    BAR();                                                                     \
    __builtin_amdgcn_s_setprio(1);                                             \
    _Pragma("unroll") for (int i = 0; i < 4; i++)                              \
      _Pragma("unroll") for (int j = 0; j < 2; j++) {                          \
        acc[i + 4][j] = MFMA_(a1[i][0], b0[j][0], acc[i + 4][j], 0, 0, 0);     \
        acc[i + 4][j] = MFMA_(a1[i][1], b0[j][1], acc[i + 4][j], 0, 0, 0); }   \
    __builtin_amdgcn_s_setprio(0);                                             \
    BAR();                                                                     \
  }

__device__ __forceinline__ void gemm256_core(const bf16* __restrict__ Agl,
                                             const bf16* __restrict__ Bgl,
                                             int bm, int bn, bf16* ldsb,
                                             floatx4 (&acc)[8][4]) {
  const int tid  = threadIdx.x;
  const int wid  = tid >> 6;
  const int lane = tid & 63;
  const int quad = lane >> 4;
  const int l15  = lane & 15;
  const int wm   = wid >> 2;   // 0..1: M-half of wave, also staging k2 chunk
  const int wn   = wid & 3;    // 0..3: N-quarter of wave, also staging row/32
  const int rb   = wn * 32;
  const int gcol = wm * 32 + (((lane & 3) * 8) ^ ((lane & 32) ? 16 : 0));
  const bf16* pA = Agl + (size_t)(bm * 256 + rb + (lane >> 2)) * E_ + gcol;
  const bf16* pB = Bgl + (size_t)(bn * 256 + rb + (lane >> 2)) * E_ + gcol;
  const int aCol = (quad * 8) ^ ((l15 & 8) ? 16 : 0);

  auto LDSP = [&](int c, int mat, int qq, int row, int col) -> bf16* {
    return ldsb + ((((c * 2 + mat) * 2 + qq) * 256 + row) * 32 + col);
  };
  auto STAGE = [&](int c, int mat, int tt, int h) {
    const bf16* g = (mat ? pB : pA) + (size_t)(h * 128) * E_ + tt * 64;
    bf16* lp = LDSP(c, mat, wm, h * 128 + rb, 0);   // wave-uniform LDS base
    async_cp16(g, lp);
    async_cp16(g + (size_t)16 * E_, lp + 16 * 32);
  };
  auto RDA = [&](int c, int qq, int i) -> bf16x8 {
    return *(const bf16x8*)LDSP(c, 0, qq, wm * 128 + i * 16 + l15, aCol);
  };
  auto RDB = [&](int c, int qq, int j) -> bf16x8 {
    return *(const bf16x8*)LDSP(c, 1, qq, wn * 64 + j * 16 + l15, aCol);
  };

  STAGE(0, 1, 0, 0); STAGE(0, 1, 0, 1);
  STAGE(0, 0, 0, 0); STAGE(0, 0, 0, 1);
  STAGE(1, 1, 1, 0); STAGE(1, 1, 1, 1);
  VMW4();
  BAR();

#pragma unroll 1
  for (int tb = 0; tb < 16; tb += 2) {
    GEMM_TILE(tb, 0)
    GEMM_TILE(tb + 1, 1)
  }
}

// ---------------------------------------------------------------------------
// K3: QKV GEMM + fused q/k-softmax.  bm-inner grid (A panels = 4 MB = one
// XCD L2, resident across all 3 rounds).  Epilogue repacks through LDS and
// streams out with NON-TEMPORAL full-line stores (keep L2 for A/W).
// ---------------------------------------------------------------------------
__global__ __launch_bounds__(512, 2) void k_gemm_qkv256(
    const bf16* __restrict__ A, const bf16* __restrict__ Wt,
    const float* __restrict__ bq, const float* __restrict__ bk,
    const float* __restrict__ bv,
    bf16* __restrict__ QTb, bf16* __restrict__ KTb, bf16* __restrict__ VT) {
  __shared__ __attribute__((aligned(16))) bf16 ldsb[2 * 2 * 2 * 256 * 32];
  const int id  = blockIdx.x;
  const int xcd = id & 7, rr = id >> 3;       // rr 0..95
  const int bm  = xcd * 8 + (rr & 7);         // bm-inner: A panel L2-resident
  const int cz  = rr >> 3;                    // 0..11 combo-outer
  const int bn  = cz & 3, z = cz >> 2;
  const bf16* Bgl = Wt + (size_t)z * E_ * E_;

  floatx4 acc[8][4] = {};
  gemm256_core(A, Bgl, bm, bn, ldsb, acc);

  const int tid  = threadIdx.x;
  const int lane = tid & 63;
  const int wid  = tid >> 6;
  const int quad = lane >> 4;
  const int l15  = lane & 15;
  const int wm   = wid >> 2, wn = wid & 3;
  const float* bias = (z == 0) ? bq : (z == 1) ? bk : bv;
  float bb[4];
#pragma unroll
  for (int j = 0; j < 4; j++) bb[j] = bias[bn * 256 + wn * 64 + j * 16 + l15];

  if (z < 2) {
    // fused softmax over the head dim (64 cols of this wave), fp32 in regs
#pragma unroll
    for (int i = 0; i < 8; i++)
#pragma unroll
      for (int r = 0; r < 4; r++) {
        float v0 = acc[i][0][r] + bb[0];
        float v1 = acc[i][1][r] + bb[1];
        float v2 = acc[i][2][r] + bb[2];
        float v3 = acc[i][3][r] + bb[3];
        float m = fmaxf(fmaxf(v0, v1), fmaxf(v2, v3));
        m = fmaxf(m, __shfl_xor(m, 1));
        m = fmaxf(m, __shfl_xor(m, 2));
        m = fmaxf(m, __shfl_xor(m, 4));
        m = fmaxf(m, __shfl_xor(m, 8));
        v0 = __expf(v0 - m); v1 = __expf(v1 - m);
        v2 = __expf(v2 - m); v3 = __expf(v3 - m);
        float s = v0 + v1 + v2 + v3;
        s += __shfl_xor(s, 1); s += __shfl_xor(s, 2);
        s += __shfl_xor(s, 4); s += __shfl_xor(s, 8);
        const float inv = 1.f / s;
        acc[i][0][r] = v0 * inv; acc[i][1][r] = v1 * inv;
        acc[i][2][r] = v2 * inv; acc[i][3][r] = v3 * inv;
      }
  } else {
#pragma unroll
    for (int i = 0; i < 8; i++)
#pragma unroll
      for (int j = 0; j < 4; j++) {
        acc[i][j][0] += bb[j]; acc[i][j][1] += bb[j];
        acc[i][j][2] += bb[j]; acc[i][j][3] += bb[j];
      }
  }

  // ---- LDS repack: [c][l] bf16 tile, XOR-swizzled (2-way max on writes) ----
  bf16* rep = ldsb;
#pragma unroll
  for (int i = 0; i < 8; i++)
#pragma unroll
    for (int j = 0; j < 4; j++) {
      const int c    = wn * 64 + j * 16 + l15;
      const int lrow = wm * 128 + i * 16 + quad * 4;
      bf16x4 rv;
      rv[0] = (bf16)acc[i][j][0]; rv[1] = (bf16)acc[i][j][1];
      rv[2] = (bf16)acc[i][j][2]; rv[3] = (bf16)acc[i][j][3];
      *(bf16x4*)&rep[(c * 256 + lrow) ^ ((c & 7) << 3)] = rv;
    }
  __syncthreads();

  bf16* OT = (z == 0) ? QTb : (z == 1) ? KTb : VT;
  const int b  = bm >> 3;
  const int lb = (bm & 7) * 256;
#pragma unroll
  for (int k = 0; k < 16; k++) {
    const int c   = k * 16 + (tid >> 5);
    const int lch = tid & 31;
    const int cg  = bn * 256 + c;
    bf16x8 v = *(const bf16x8*)&rep[(c * 256 + lch * 8) ^ ((c & 7) << 3)];
    nt_store16(v, &OT[((size_t)((b * 16 + (cg >> 6)) * 64 + (cg & 63))) * 2048 + lb + lch * 8]);
  }
}

// ---------------------------------------------------------------------------
// K7: final projection GEMM, 256^2 8-phase.  nt fp32 stores (output never
// re-read on device).
// ---------------------------------------------------------------------------
__global__ __launch_bounds__(512, 2) void k_gemm_final256(
    const bf16* __restrict__ A, const bf16* __restrict__ Bt,
    const float* __restrict__ bias, float* __restrict__ C) {
  __shared__ __attribute__((aligned(16))) bf16 ldsb[2 * 2 * 2 * 256 * 32];
  const int id  = blockIdx.x;
  const int xcd = id & 7, rr = id >> 3;       // rr 0..31
  const int bm  = xcd * 8 + (rr >> 2);
  const int bn  = rr & 3;

  floatx4 acc[8][4] = {};
  gemm256_core(A, Bt, bm, bn, ldsb, acc);

  const int tid  = threadIdx.x;
  const int wid  = tid >> 6;
  const int lane = tid & 63;
  const int quad = lane >> 4;
  const int l15  = lane & 15;
  const int wm   = wid >> 2, wn = wid & 3;
#pragma unroll
  for (int i = 0; i < 8; i++)
#pragma unroll
    for (int j = 0; j < 4; j++) {
      const int col = bn * 256 + wn * 64 + j * 16 + l15;
      const float bb = bias[col];
#pragma unroll
      for (int r = 0; r < 4; r++) {
        const int row = bm * 256 + wm * 128 + i * 16 + quad * 4 + r;
        __builtin_nontemporal_store(acc[i][j][r] + bb, &C[(size_t)row * E_ + col]);
      }
    }
}

// ---------------------------------------------------------------------------
// K4: KV GEMM from bf16 K-probs.  Double-buffered staging, 2 barriers/iter:
//  sync (drain stage i) -> issue stage(i+1)+trig(i+1) -> build/rowsum(i)
//  -> lgkmcnt(0); s_barrier (cp16s stay in flight) -> MFMA(i).
// ---------------------------------------------------------------------------
__global__ __launch_bounds__(256) void k_kv(const bf16* __restrict__ KTb,
                                            const bf16* __restrict__ VT,
                                            float* __restrict__ kvp) {
  __shared__ __attribute__((aligned(16))) bf16 ktb[2][64 * 32];  // 8 KB (swz)
  __shared__ __attribute__((aligned(16))) bf16 vt[2][64 * 32];   // 8 KB
  __shared__ __attribute__((aligned(16))) bf16 Bsn[64 * 40];     // 5 KB
  __shared__ __attribute__((aligned(16))) bf16 Bcs[64 * 40];     // 5 KB
  __shared__ float snl[2][32], csl[2][32];
  const int kseg = blockIdx.x;
  const int bh   = blockIdx.y;
  const int t = threadIdx.x;
  const int wid = t >> 6, lane = t & 63;
  const int quad = lane >> 4, l15 = lane & 15;
  const int wm = wid >> 1, wn = wid & 1;

  const bf16* ktg = KTb + (size_t)bh * 64 * 2048;
  const bf16* vtg = VT  + (size_t)bh * 64 * 2048;

  const int sr = lane >> 2, sch = lane & 3;  // staging row/chunk within wave

  auto STG = [&](int it, int nb) {
    const int l0 = kseg * 512 + it * 32;
    const bf16* gk = ktg + (size_t)(wid * 16 + sr) * 2048 + l0 + ((sch ^ (sr & 1)) * 8);
    async_cp16(gk, &ktb[nb][(wid * 16) * 32]);
    const bf16* gv = vtg + (size_t)(wid * 16 + sr) * 2048 + l0 + sch * 8;
    async_cp16(gv, &vt[nb][(wid * 16) * 32]);
  };

  floatx4 acc[4][2] = {};
  float rs = 0.f;
  const int d_ = t & 63, h_ = t >> 6;   // rowsum role (t<128)

  STG(0, 0);
  if (t < 32) {
    const float ang = PI2_ * (float)(kseg * 512 + t + 1) / (float)L_;
    snl[0][t] = __sinf(ang); csl[0][t] = __cosf(ang);
  }

  for (int it = 0; it < 16; it++) {
    const int b = it & 1;
    __syncthreads();   // drains vmcnt(0): stage(it) landed; trig(it) visible

    if (it + 1 < 16) {
      STG(it + 1, b ^ 1);
      if (t < 32) {
        const float ang = PI2_ * (float)(kseg * 512 + (it + 1) * 32 + t + 1) / (float)L_;
        snl[(it + 1) & 1][t] = __sinf(ang); csl[(it + 1) & 1][t] = __cosf(ang);
      }
    }

    // build Bsn/Bcs from vt[b] (each thread: one bf16x8 chunk)
    {
      const int row = t >> 2, cc = (t & 3) * 8;
      bf16x8 v = *(const bf16x8*)&vt[b][row * 32 + cc];
      bf16x8 a, c;
#pragma unroll
      for (int e = 0; e < 8; e++) {
        const float f = (float)v[e];
        a[e] = (bf16)(f * snl[b][cc + e]);
        c[e] = (bf16)(f * csl[b][cc + e]);
      }
      *(bf16x8*)&Bsn[row * 40 + cc] = a;
      *(bf16x8*)&Bcs[row * 40 + cc] = c;
    }
    // rowsums (ks partials) from swizzled ktb[b]
    if (t < 128) {
      float r8 = 0.f;
#pragma unroll
      for (int p = 0; p < 4; p++) {
        bf16x8 v = *(const bf16x8*)&ktb[b][d_ * 32 + p * 8];
        const int gl = (p ^ (d_ & 1)) * 8;
#pragma unroll
        for (int e = 0; e < 8; e++)
          r8 += (float)v[e] * (h_ ? csl[b][gl + e] : snl[b][gl + e]);
      }
      rs += r8;
    }
    LGKM0(); BAR();    // ds_writes visible; staged cp16s stay in flight

    bf16x8 af[4], bfm[2];
    const bf16* Bsel = wm ? Bcs : Bsn;
#pragma unroll
    for (int i = 0; i < 4; i++)
      af[i] = *(const bf16x8*)&ktb[b][(i * 16 + l15) * 32 + ((quad ^ (l15 & 1)) * 8)];
#pragma unroll
    for (int j = 0; j < 2; j++)
      bfm[j] = *(const bf16x8*)&Bsel[(wn * 32 + j * 16 + l15) * 40 + quad * 8];
#pragma unroll
    for (int i = 0; i < 4; i++)
#pragma unroll
      for (int j = 0; j < 2; j++)
        acc[i][j] = __builtin_amdgcn_mfma_f32_16x16x32_bf16(af[i], bfm[j], acc[i][j], 0, 0, 0);
  }

  float* C = kvp + (size_t)(kseg * 128 + bh) * 128 * 68;
#pragma unroll
  for (int i = 0; i < 4; i++)
#pragma unroll
    for (int j = 0; j < 2; j++) {
      const int col = wn * 32 + j * 16 + l15;
#pragma unroll
      for (int r = 0; r < 4; r++) {
        const int row = wm * 64 + i * 16 + quad * 4 + r;
        __builtin_nontemporal_store(acc[i][j][r], &C[(size_t)row * 68 + col]);
      }
    }
  if (t < 128) __builtin_nontemporal_store(rs, &C[(size_t)t * 68 + 64]);
}

// ---------------------------------------------------------------------------
// K5: consts (256 threads: 4-way f-chunk parallelism + LDS reduce).
// ---------------------------------------------------------------------------
__global__ __launch_bounds__(256) void k_consts(const float* __restrict__ kvp,
                                                bf16* __restrict__ KVT,
                                                float* __restrict__ ksbuf) {
  __shared__ float red[4][64];
  __shared__ float sksh[2];
  const int bh = blockIdx.x;
  const int t  = threadIdx.x;
  const int fq = t >> 6, dp = t & 63;
  const size_t gs = (size_t)128 * 128 * 68;
  const float* P = kvp + (size_t)bh * 128 * 68;
  bf16* kr = KVT + (size_t)(bh * 64 + dp) * 160;
  float sp = 0.f;
#pragma unroll 8
  for (int f = fq * 32; f < fq * 32 + 32; f++) {
    float v = P[(size_t)f * 68 + dp] + P[gs + (size_t)f * 68 + dp]
            + P[2 * gs + (size_t)f * 68 + dp] + P[3 * gs + (size_t)f * 68 + dp];
    kr[f] = (bf16)v;
    sp += v;
  }
  red[fq][dp] = sp;
  float ksv = 0.f;
  if (t < 128) {
    ksv = P[(size_t)t * 68 + 64] + P[gs + (size_t)t * 68 + 64]
        + P[2 * gs + (size_t)t * 68 + 64] + P[3 * gs + (size_t)t * 68 + 64];
    ksbuf[(size_t)bh * 136 + t] = ksv;
  }
  float sks = ksv;
#pragma unroll
  for (int o = 1; o < 64; o <<= 1) sks += __shfl_xor(sks, o);
  if (t == 0)  sksh[0] = sks;   // sum of ks0 (wave 0)
  if (t == 64) sksh[1] = sks;   // sum of ks1 (wave 1)
  __syncthreads();
  if (t < 64) {
    const float sk0 = red[0][t] + red[1][t];
    const float sk1 = red[2][t] + red[3][t];
    kr[128] = (bf16)(62.f * sk0);
    kr[129] = (bf16)(62.f * sk1);
#pragma unroll
    for (int f = 130; f < 160; f++) kr[f] = (bf16)0.f;
    if (t == 0) {
      ksbuf[(size_t)bh * 136 + 128] = sksh[0];
      ksbuf[(size_t)bh * 136 + 129] = sksh[1];
    }
  }
}

// ---------------------------------------------------------------------------
// K6: fused attention.  nt q-loads (read-once stream); output repacked
// through LDS (stride-72) and streamed with nt full-line stores.
// ---------------------------------------------------------------------------
#define ASTR 168
#define OSTR 72
__global__ __launch_bounds__(256) void k_attn(const bf16* __restrict__ QTb,
                                              const bf16* __restrict__ KVT,
                                              const float* __restrict__ ksbuf,
                                              bf16* __restrict__ attn) {
  __shared__ __attribute__((aligned(16))) bf16 Abuf[128 * ASTR];
  __shared__ __attribute__((aligned(16))) bf16 Bbuf[64 * ASTR];
  __shared__ float ksl[136];
  __shared__ float pth0[2][128], pth1[2][128];
  const int lc = blockIdx.x;   // 0..15
  const int bh = blockIdx.y;
  const int b = bh >> 4, h = bh & 15;
  const int t = threadIdx.x;

  {
    const bf16* src = KVT + (size_t)bh * 64 * 160;
#pragma unroll
    for (int i = 0; i < 5; i++) {
      const int idx = t + i * 256;
      const int row = idx / 20, ch = idx % 20;
      *(bf16x8*)&Bbuf[row * ASTR + ch * 8] = *(const bf16x8*)(src + row * 160 + ch * 8);
    }
    if (t < 130) ksl[t] = ksbuf[(size_t)bh * 136 + t];
  }
  __syncthreads();

  const int lr = t & 127, hf = t >> 7;
  const int l  = lc * 128 + lr;
  float xv[32];
  {
    const bf16* qp = QTb + (size_t)bh * 64 * 2048 + (size_t)(hf * 32) * 2048 + l;
#pragma unroll
    for (int d = 0; d < 32; d++) xv[d] = ld_bf16_nt(qp + (size_t)d * 2048);
    float pa = 0.f, pb = 0.f;
#pragma unroll
    for (int d = 0; d < 32; d++) {
      pa += xv[d] * ksl[hf * 32 + d];
      pb += xv[d] * ksl[64 + hf * 32 + d];
    }
    pth0[hf][lr] = pa; pth1[hf][lr] = pb;
  }
  __syncthreads();

  {
    const float t0 = pth0[0][lr] + pth0[1][lr];
    const float t1 = pth1[0][lr] + pth1[1][lr];
    const float SKS0 = ksl[128], SKS1 = ksl[129];
    const float ang = PI2_ * (float)(l + 1) / (float)L_;
    const float sn = __sinf(ang), cs = __cosf(ang);
    const float den1 = sn * t0 + cs * t1;
    const float den2 = sn * (62.f * SKS0 + t0) + cs * (62.f * SKS1 + t1);
    const float z1 = 1.f / fmaxf(den1, EPS_);
    const float z2 = 1.f / fmaxf(den2, EPS_);
    const float zz = z1 + z2;
    const float a0 = zz * sn, a1 = zz * cs;
    bf16* ar = &Abuf[lr * ASTR];
#pragma unroll
    for (int g = 0; g < 4; g++) {
      bf16x8 w;
#pragma unroll
      for (int j = 0; j < 8; j++) w[j] = (bf16)(a0 * xv[g * 8 + j]);
      *(bf16x8*)(ar + hf * 32 + g * 8) = w;
    }
#pragma unroll
    for (int g = 0; g < 4; g++) {
      bf16x8 w;
#pragma unroll
      for (int j = 0; j < 8; j++) w[j] = (bf16)(a1 * xv[g * 8 + j]);
      *(bf16x8*)(ar + 64 + hf * 32 + g * 8) = w;
    }
    if (hf) {
      bf16x8 wt = {};
      wt[0] = (bf16)(z2 * sn); wt[1] = (bf16)(z2 * cs);
      *(bf16x8*)(ar + 128) = wt;
      bf16x8 zr = {};
      *(bf16x8*)(ar + 136) = zr;
      *(bf16x8*)(ar + 144) = zr;
      *(bf16x8*)(ar + 152) = zr;
    }
  }
  __syncthreads();

  const int wid = t >> 6, lane = t & 63;
  const int quad = lane >> 4, l15 = lane & 15;
  const int wm = wid >> 1, wn = wid & 1;
  floatx4 acc[4][2] = {};
#pragma unroll
  for (int kk = 0; kk < 5; kk++) {
    bf16x8 af[4], bfm[2];
#pragma unroll
    for (int i = 0; i < 4; i++)
      af[i] = *(const bf16x8*)&Abuf[(wm * 64 + i * 16 + l15) * ASTR + kk * 32 + quad * 8];
#pragma unroll
    for (int j = 0; j < 2; j++)
      bfm[j] = *(const bf16x8*)&Bbuf[(wn * 32 + j * 16 + l15) * ASTR + kk * 32 + quad * 8];
#pragma unroll
    for (int i = 0; i < 4; i++)
#pragma unroll
      for (int j = 0; j < 2; j++)
        acc[i][j] = __builtin_amdgcn_mfma_f32_16x16x32_bf16(af[i], bfm[j], acc[i][j], 0, 0, 0);
  }

  // ---- out repack: [l local][64] bf16, stride 72; then nt full-line burst --
  __syncthreads();   // all Abuf MFMA reads done
  bf16* ob = Abuf;
#pragma unroll
  for (int i = 0; i < 4; i++)
#pragma unroll
    for (int j = 0; j < 2; j++) {
      const int dp = wn * 32 + j * 16 + l15;
#pragma unroll
      for (int r = 0; r < 4; r++) {
        const int ll = wm * 64 + i * 16 + quad * 4 + r;
        ob[ll * OSTR + dp] = (bf16)acc[i][j][r];
      }
    }
  __syncthreads();
  {
    const int ll = t >> 1, half = t & 1;
    const size_t gbase = ((size_t)(lc * 128 + ll) * B_ + b) * E_ + h * 64 + half * 32;
#pragma unroll
    for (int g = 0; g < 4; g++) {
      bf16x8 v = *(const bf16x8*)&ob[ll * OSTR + half * 32 + g * 8];
      nt_store16(v, &attn[gbase + g * 8]);
    }
  }
}

// ---------------------------------------------------------------------------
// Workspace layout (bytes), total 163,123,200 (<= 243,269,632):
//  QTb   bf16 [128][64][2048]  @ 0             (33,554,432)
//  KTb   bf16 [128][64][2048]  @  33,554,432   (33,554,432)
//  VT    bf16 [128][64][2048]  @  67,108,864   (33,554,432)
//  Wt    bf16 x4               @ 100,663,296   ( 8,388,608)
//  Xbf   bf16                  @ 109,051,904   (33,554,432) -> attnb overlay
//  kvp   fp32 [4][128][128][68]@ 142,606,336   (17,825,792)
//  KVT   bf16 [128][64][160]   @ 160,432,128   ( 2,621,440)
//  ksbuf fp32 [128][136]       @ 163,053,568   (    69,632)
// ---------------------------------------------------------------------------
extern "C" void kernel_launch(void* const* d_in, const int* in_sizes, int n_in,
                              void* d_out, int out_size, void* d_ws, size_t ws_size,
                              hipStream_t stream) {
  (void)in_sizes; (void)n_in; (void)out_size; (void)ws_size;
  const float* query = (const float*)d_in[0];
  const float* Wq = (const float*)d_in[1];
  const float* bq = (const float*)d_in[2];
  const float* Wk = (const float*)d_in[3];
  const float* bk = (const float*)d_in[4];
  const float* Wv = (const float*)d_in[5];
  const float* bv = (const float*)d_in[6];
  const float* Wo = (const float*)d_in[7];
  const float* bo = (const float*)d_in[8];

  char* ws = (char*)d_ws;
  bf16*  QTb  = (bf16*) (ws + 0);
  bf16*  KTb  = (bf16*) (ws + 33554432);
  bf16*  VT   = (bf16*) (ws + 67108864);
  bf16*  Wt   = (bf16*) (ws + 100663296);
  bf16*  Xbf  = (bf16*) (ws + 109051904);
  bf16*  attnb= (bf16*) (ws + 109051904);
  float* kvp  = (float*)(ws + 142606336);
  bf16*  KVT  = (bf16*) (ws + 160432128);
  float* ksbuf= (float*)(ws + 163053568);

  // 1) X -> bf16
  k_convert_x<<<(M_ * E_) / (256 * 8), 256, 0, stream>>>(query, Xbf);

  // 2) W^T -> bf16 for all four weights
  TArgs ta;
  ta.src[0] = Wq; ta.src[1] = Wk; ta.src[2] = Wv; ta.src[3] = Wo;
  ta.dst[0] = Wt;                       ta.dst[1] = Wt + (size_t)E_ * E_;
  ta.dst[2] = Wt + (size_t)2 * E_ * E_; ta.dst[3] = Wt + (size_t)3 * E_ * E_;
  k_transpose_w<<<dim3(32, 32, 4), dim3(32, 8), 0, stream>>>(ta);

  // 3) QKV GEMM + fused q/k-softmax (nt full-line stores, bm-inner grid)
  k_gemm_qkv256<<<768, 512, 0, stream>>>(Xbf, Wt, bq, bk, bv, QTb, KTb, VT);

  // 4) KV GEMM from bf16 probs (2-barrier double-buffered)
  k_kv<<<dim3(4, 128), 256, 0, stream>>>(KTb, VT, kvp);

  // 5) consts: KVT + ksbuf
  k_consts<<<128, 256, 0, stream>>>(kvp, KVT, ksbuf);

  // 6) fused attention
  k_attn<<<dim3(16, 128), 256, 0, stream>>>(QTb, KVT, ksbuf, attnb);

  // 7) final projection -> d_out
  k_gemm_final256<<<256, 512, 0, stream>>>(attnb, Wt + (size_t)3 * E_ * E_, bo, (float*)d_out);
}

// Round 6
// 349.494 us; speedup vs baseline: 1.0656x; 1.0656x over previous
//
#include <hip/hip_runtime.h>
#include <hip/hip_bf16.h>
#include <cstdint>

// Problem constants
#define B_   8
#define L_   2048
#define E_   1024
#define H_   16
#define D_   64
#define M_   (B_ * L_)
#define EPS_ 1e-6f
#define PI2_ 1.57079632679f

typedef __bf16 bf16;
typedef __bf16 bf16x8 __attribute__((ext_vector_type(8)));
typedef __bf16 bf16x4 __attribute__((ext_vector_type(4)));
typedef float  floatx4 __attribute__((ext_vector_type(4)));
typedef unsigned int uintx4 __attribute__((ext_vector_type(4)));

__device__ inline void async_cp16(const void* g, void* l) {
  __builtin_amdgcn_global_load_lds(
      (__attribute__((address_space(1))) void*)const_cast<void*>(g),
      (__attribute__((address_space(3))) void*)l,
      16, 0, 0);
}

// ---------------------------------------------------------------------------
// K1: fp32 -> bf16 convert (query -> Xbf).  nt loads (query read once; never
// re-read on device -> keep it out of L2/L3).
// ---------------------------------------------------------------------------
__global__ __launch_bounds__(256) void k_convert_x(const float* __restrict__ x,
                                                   bf16* __restrict__ o) {
  size_t i = ((size_t)blockIdx.x * 256 + threadIdx.x) * 8;
  floatx4 a = __builtin_nontemporal_load(reinterpret_cast<const floatx4*>(x + i));
  floatx4 b = __builtin_nontemporal_load(reinterpret_cast<const floatx4*>(x + i + 4));
  bf16x8 r;
  r[0] = (bf16)a[0]; r[1] = (bf16)a[1]; r[2] = (bf16)a[2]; r[3] = (bf16)a[3];
  r[4] = (bf16)b[0]; r[5] = (bf16)b[1]; r[6] = (bf16)b[2]; r[7] = (bf16)b[3];
  *(bf16x8*)(o + i) = r;
}

// ---------------------------------------------------------------------------
// K2: transpose 4 weight matrices (E x E fp32 (in,out)) -> bf16 (out,in)
// ---------------------------------------------------------------------------
struct TArgs { const float* src[4]; bf16* dst[4]; };

__global__ __launch_bounds__(256) void k_transpose_w(TArgs t) {
  __shared__ float tile[32][33];
  const float* src = t.src[blockIdx.z];
  bf16* dst = t.dst[blockIdx.z];
  int bx = blockIdx.x, by = blockIdx.y;
  int x = threadIdx.x, y = threadIdx.y;  // (32, 8)
#pragma unroll
  for (int i = 0; i < 4; i++) {
    int r = by * 32 + y + i * 8;
    tile[y + i * 8][x] = src[(size_t)r * E_ + bx * 32 + x];
  }
  __syncthreads();
#pragma unroll
  for (int i = 0; i < 4; i++) {
    int r = bx * 32 + y + i * 8;
    dst[(size_t)r * E_ + by * 32 + x] = (bf16)tile[x][y + i * 8];
  }
}

// ---------------------------------------------------------------------------
// 256x256x64 8-phase GEMM core (T1+T2+T3/T4+T5).  8 waves = 2(M) x 4(N);
// per-wave output 128x64; NT=16 K-tiles; LDS st-swizzle via pre-swizzled
// global source (linear global_load_lds dest) + swizzled ds_read; counted
// vmcnt(4) once per tile, never 0 in steady state.
// ---------------------------------------------------------------------------
#define BAR()   asm volatile("s_barrier" ::: "memory")
#define LGKM0() asm volatile("s_waitcnt lgkmcnt(0)" ::: "memory")
#define VMW4()  asm volatile("s_waitcnt vmcnt(4)" ::: "memory")
#define VMW0()  asm volatile("s_waitcnt vmcnt(0)" ::: "memory")
#define MFMA_   __builtin_amdgcn_mfma_f32_16x16x32_bf16

#define GEMM_TILE(t_, c_) {                                                    \
    const int t = (t_); const int c = (c_);                                    \
    bf16x8 a0[4][2], a1[4][2], b0[2][2], b1[2][2];                             \
    /* phase 0 */                                                              \
    _Pragma("unroll") for (int i = 0; i < 4; i++) {                            \
      a0[i][0] = RDA(c, 0, i); a0[i][1] = RDA(c, 1, i); }                      \
    _Pragma("unroll") for (int j = 0; j < 2; j++) {                            \
      b0[j][0] = RDB(c, 0, j); b0[j][1] = RDB(c, 1, j); }                      \
    if (t + 1 < 16) STAGE(c ^ 1, 0, t + 1, 0);                                 \
    BAR(); LGKM0();                                                            \
    __builtin_amdgcn_s_setprio(1);                                             \
    _Pragma("unroll") for (int i = 0; i < 4; i++)                              \
      _Pragma("unroll") for (int j = 0; j < 2; j++) {                          \
        acc[i][j] = MFMA_(a0[i][0], b0[j][0], acc[i][j], 0, 0, 0);             \
        acc[i][j] = MFMA_(a0[i][1], b0[j][1], acc[i][j], 0, 0, 0); }           \
    __builtin_amdgcn_s_setprio(0);                                             \
    BAR();                                                                     \
    /* phase 1 */                                                              \
    _Pragma("unroll") for (int j = 0; j < 2; j++) {                            \
      b1[j][0] = RDB(c, 0, j + 2); b1[j][1] = RDB(c, 1, j + 2); }              \
    if (t + 1 < 16) STAGE(c ^ 1, 0, t + 1, 1);                                 \
    BAR(); LGKM0();                                                            \
    __builtin_amdgcn_s_setprio(1);                                             \
    _Pragma("unroll") for (int i = 0; i < 4; i++)                              \
      _Pragma("unroll") for (int j = 0; j < 2; j++) {                          \
        acc[i][j + 2] = MFMA_(a0[i][0], b1[j][0], acc[i][j + 2], 0, 0, 0);     \
        acc[i][j + 2] = MFMA_(a0[i][1], b1[j][1], acc[i][j + 2], 0, 0, 0); }   \
    __builtin_amdgcn_s_setprio(0);                                             \
    BAR();                                                                     \
    /* phase 2 */                                                              \
    _Pragma("unroll") for (int i = 0; i < 4; i++) {                            \
      a1[i][0] = RDA(c, 0, i + 4); a1[i][1] = RDA(c, 1, i + 4); }              \
    if (t + 2 < 16) STAGE(c, 1, t + 2, 0);                                     \
    BAR(); LGKM0();                                                            \
    __builtin_amdgcn_s_setprio(1);                                             \
    _Pragma("unroll") for (int i = 0; i < 4; i++)                              \
      _Pragma("unroll") for (int j = 0; j < 2; j++) {                          \
        acc[i + 4][j + 2] = MFMA_(a1[i][0], b1[j][0], acc[i + 4][j + 2], 0, 0, 0); \
        acc[i + 4][j + 2] = MFMA_(a1[i][1], b1[j][1], acc[i + 4][j + 2], 0, 0, 0); } \
    __builtin_amdgcn_s_setprio(0);                                             \
    BAR();                                                                     \
    /* phase 3 */                                                              \
    if (t < 14) { STAGE(c, 1, t + 2, 1); VMW4(); } else { VMW0(); }            \
    BAR();                                                                     \
    __builtin_amdgcn_s_setprio(1);                                             \
    _Pragma("unroll") for (int i = 0; i < 4; i++)                              \
      _Pragma("unroll") for (int j = 0; j < 2; j++) {                          \
        acc[i + 4][j] = MFMA_(a1[i][0], b0[j][0], acc[i + 4][j], 0, 0, 0);     \
        acc[i + 4][j] = MFMA_(a1[i][1], b0[j][1], acc[i + 4][j], 0, 0, 0); }   \
    __builtin_amdgcn_s_setprio(0);                                             \
    BAR();                                                                     \
  }

__device__ __forceinline__ void gemm256_core(const bf16* __restrict__ Agl,
                                             const bf16* __restrict__ Bgl,
                                             int bm, int bn, bf16* ldsb,
                                             floatx4 (&acc)[8][4]) {
  const int tid  = threadIdx.x;
  const int wid  = tid >> 6;
  const int lane = tid & 63;
  const int quad = lane >> 4;
  const int l15  = lane & 15;
  const int wm   = wid >> 2;   // 0..1: M-half of wave, also staging k2 chunk
  const int wn   = wid & 3;    // 0..3: N-quarter of wave, also staging row/32
  const int rb   = wn * 32;
  const int gcol = wm * 32 + (((lane & 3) * 8) ^ ((lane & 32) ? 16 : 0));
  const bf16* pA = Agl + (size_t)(bm * 256 + rb + (lane >> 2)) * E_ + gcol;
  const bf16* pB = Bgl + (size_t)(bn * 256 + rb + (lane >> 2)) * E_ + gcol;
  const int aCol = (quad * 8) ^ ((l15 & 8) ? 16 : 0);

  auto LDSP = [&](int c, int mat, int qq, int row, int col) -> bf16* {
    return ldsb + ((((c * 2 + mat) * 2 + qq) * 256 + row) * 32 + col);
  };
  auto STAGE = [&](int c, int mat, int tt, int h) {
    const bf16* g = (mat ? pB : pA) + (size_t)(h * 128) * E_ + tt * 64;
    bf16* lp = LDSP(c, mat, wm, h * 128 + rb, 0);   // wave-uniform LDS base
    async_cp16(g, lp);
    async_cp16(g + (size_t)16 * E_, lp + 16 * 32);
  };
  auto RDA = [&](int c, int qq, int i) -> bf16x8 {
    return *(const bf16x8*)LDSP(c, 0, qq, wm * 128 + i * 16 + l15, aCol);
  };
  auto RDB = [&](int c, int qq, int j) -> bf16x8 {
    return *(const bf16x8*)LDSP(c, 1, qq, wn * 64 + j * 16 + l15, aCol);
  };

  STAGE(0, 1, 0, 0); STAGE(0, 1, 0, 1);
  STAGE(0, 0, 0, 0); STAGE(0, 0, 0, 1);
  STAGE(1, 1, 1, 0); STAGE(1, 1, 1, 1);
  VMW4();
  BAR();

#pragma unroll 1
  for (int tb = 0; tb < 16; tb += 2) {
    GEMM_TILE(tb, 0)
    GEMM_TILE(tb + 1, 1)
  }
}

// ---------------------------------------------------------------------------
// K3: QKV GEMM + fused q/k-softmax.  bm-inner grid (A panels L2-resident).
// Epilogue repacks through LDS; NORMAL full-line stores (outputs are re-read
// by k_kv/k_attn -> keep them cacheable; nt here cost ~20us downstream, R5).
// ---------------------------------------------------------------------------
__global__ __launch_bounds__(512, 2) void k_gemm_qkv256(
    const bf16* __restrict__ A, const bf16* __restrict__ Wt,
    const float* __restrict__ bq, const float* __restrict__ bk,
    const float* __restrict__ bv,
    bf16* __restrict__ QTb, bf16* __restrict__ KTb, bf16* __restrict__ VT) {
  __shared__ __attribute__((aligned(16))) bf16 ldsb[2 * 2 * 2 * 256 * 32];
  const int id  = blockIdx.x;
  const int xcd = id & 7, rr = id >> 3;       // rr 0..95
  const int bm  = xcd * 8 + (rr & 7);         // bm-inner: A panel L2-resident
  const int cz  = rr >> 3;                    // 0..11 combo-outer
  const int bn  = cz & 3, z = cz >> 2;
  const bf16* Bgl = Wt + (size_t)z * E_ * E_;

  floatx4 acc[8][4] = {};
  gemm256_core(A, Bgl, bm, bn, ldsb, acc);

  const int tid  = threadIdx.x;
  const int lane = tid & 63;
  const int wid  = tid >> 6;
  const int quad = lane >> 4;
  const int l15  = lane & 15;
  const int wm   = wid >> 2, wn = wid & 3;
  const float* bias = (z == 0) ? bq : (z == 1) ? bk : bv;
  float bb[4];
#pragma unroll
  for (int j = 0; j < 4; j++) bb[j] = bias[bn * 256 + wn * 64 + j * 16 + l15];

  if (z < 2) {
    // fused softmax over the head dim (64 cols of this wave), fp32 in regs
#pragma unroll
    for (int i = 0; i < 8; i++)
#pragma unroll
      for (int r = 0; r < 4; r++) {
        float v0 = acc[i][0][r] + bb[0];
        float v1 = acc[i][1][r] + bb[1];
        float v2 = acc[i][2][r] + bb[2];
        float v3 = acc[i][3][r] + bb[3];
        float m = fmaxf(fmaxf(v0, v1), fmaxf(v2, v3));
        m = fmaxf(m, __shfl_xor(m, 1));
        m = fmaxf(m, __shfl_xor(m, 2));
        m = fmaxf(m, __shfl_xor(m, 4));
        m = fmaxf(m, __shfl_xor(m, 8));
        v0 = __expf(v0 - m); v1 = __expf(v1 - m);
        v2 = __expf(v2 - m); v3 = __expf(v3 - m);
        float s = v0 + v1 + v2 + v3;
        s += __shfl_xor(s, 1); s += __shfl_xor(s, 2);
        s += __shfl_xor(s, 4); s += __shfl_xor(s, 8);
        const float inv = 1.f / s;
        acc[i][0][r] = v0 * inv; acc[i][1][r] = v1 * inv;
        acc[i][2][r] = v2 * inv; acc[i][3][r] = v3 * inv;
      }
  } else {
#pragma unroll
    for (int i = 0; i < 8; i++)
#pragma unroll
      for (int j = 0; j < 4; j++) {
        acc[i][j][0] += bb[j]; acc[i][j][1] += bb[j];
        acc[i][j][2] += bb[j]; acc[i][j][3] += bb[j];
      }
  }

  // ---- LDS repack: [c][l] bf16 tile, XOR-swizzled (2-way max on writes) ----
  bf16* rep = ldsb;
#pragma unroll
  for (int i = 0; i < 8; i++)
#pragma unroll
    for (int j = 0; j < 4; j++) {
      const int c    = wn * 64 + j * 16 + l15;
      const int lrow = wm * 128 + i * 16 + quad * 4;
      bf16x4 rv;
      rv[0] = (bf16)acc[i][j][0]; rv[1] = (bf16)acc[i][j][1];
      rv[2] = (bf16)acc[i][j][2]; rv[3] = (bf16)acc[i][j][3];
      *(bf16x4*)&rep[(c * 256 + lrow) ^ ((c & 7) << 3)] = rv;
    }
  __syncthreads();

  bf16* OT = (z == 0) ? QTb : (z == 1) ? KTb : VT;
  const int b  = bm >> 3;
  const int lb = (bm & 7) * 256;
#pragma unroll
  for (int k = 0; k < 16; k++) {
    const int c   = k * 16 + (tid >> 5);
    const int lch = tid & 31;
    const int cg  = bn * 256 + c;
    bf16x8 v = *(const bf16x8*)&rep[(c * 256 + lch * 8) ^ ((c & 7) << 3)];
    *(bf16x8*)&OT[((size_t)((b * 16 + (cg >> 6)) * 64 + (cg & 63))) * 2048 + lb + lch * 8] = v;
  }
}

// ---------------------------------------------------------------------------
// K7: final projection GEMM, 256^2 8-phase.  nt fp32 stores (d_out is a true
// export: never re-read on device).
// ---------------------------------------------------------------------------
__global__ __launch_bounds__(512, 2) void k_gemm_final256(
    const bf16* __restrict__ A, const bf16* __restrict__ Bt,
    const float* __restrict__ bias, float* __restrict__ C) {
  __shared__ __attribute__((aligned(16))) bf16 ldsb[2 * 2 * 2 * 256 * 32];
  const int id  = blockIdx.x;
  const int xcd = id & 7, rr = id >> 3;       // rr 0..31
  const int bm  = xcd * 8 + (rr >> 2);
  const int bn  = rr & 3;

  floatx4 acc[8][4] = {};
  gemm256_core(A, Bt, bm, bn, ldsb, acc);

  const int tid  = threadIdx.x;
  const int wid  = tid >> 6;
  const int lane = tid & 63;
  const int quad = lane >> 4;
  const int l15  = lane & 15;
  const int wm   = wid >> 2, wn = wid & 3;
#pragma unroll
  for (int i = 0; i < 8; i++)
#pragma unroll
    for (int j = 0; j < 4; j++) {
      const int col = bn * 256 + wn * 64 + j * 16 + l15;
      const float bb = bias[col];
#pragma unroll
      for (int r = 0; r < 4; r++) {
        const int row = bm * 256 + wm * 128 + i * 16 + quad * 4 + r;
        __builtin_nontemporal_store(acc[i][j][r] + bb, &C[(size_t)row * E_ + col]);
      }
    }
}

// ---------------------------------------------------------------------------
// K4: KV GEMM from bf16 K-probs.  Double-buffered staging, 2 barriers/iter:
//  sync (drain stage i) -> issue stage(i+1)+trig(i+1) -> build/rowsum(i)
//  -> lgkmcnt(0); s_barrier (cp16s stay in flight) -> MFMA(i).
//  Normal kvp stores (read by k_consts immediately after).
// ---------------------------------------------------------------------------
__global__ __launch_bounds__(256) void k_kv(const bf16* __restrict__ KTb,
                                            const bf16* __restrict__ VT,
                                            float* __restrict__ kvp) {
  __shared__ __attribute__((aligned(16))) bf16 ktb[2][64 * 32];  // 8 KB (swz)
  __shared__ __attribute__((aligned(16))) bf16 vt[2][64 * 32];   // 8 KB
  __shared__ __attribute__((aligned(16))) bf16 Bsn[64 * 40];     // 5 KB
  __shared__ __attribute__((aligned(16))) bf16 Bcs[64 * 40];     // 5 KB
  __shared__ float snl[2][32], csl[2][32];
  const int kseg = blockIdx.x;
  const int bh   = blockIdx.y;
  const int t = threadIdx.x;
  const int wid = t >> 6, lane = t & 63;
  const int quad = lane >> 4, l15 = lane & 15;
  const int wm = wid >> 1, wn = wid & 1;

  const bf16* ktg = KTb + (size_t)bh * 64 * 2048;
  const bf16* vtg = VT  + (size_t)bh * 64 * 2048;

  const int sr = lane >> 2, sch = lane & 3;  // staging row/chunk within wave

  auto STG = [&](int it, int nb) {
    const int l0 = kseg * 512 + it * 32;
    const bf16* gk = ktg + (size_t)(wid * 16 + sr) * 2048 + l0 + ((sch ^ (sr & 1)) * 8);
    async_cp16(gk, &ktb[nb][(wid * 16) * 32]);
    const bf16* gv = vtg + (size_t)(wid * 16 + sr) * 2048 + l0 + sch * 8;
    async_cp16(gv, &vt[nb][(wid * 16) * 32]);
  };

  floatx4 acc[4][2] = {};
  float rs = 0.f;
  const int d_ = t & 63, h_ = t >> 6;   // rowsum role (t<128)

  STG(0, 0);
  if (t < 32) {
    const float ang = PI2_ * (float)(kseg * 512 + t + 1) / (float)L_;
    snl[0][t] = __sinf(ang); csl[0][t] = __cosf(ang);
  }

  for (int it = 0; it < 16; it++) {
    const int b = it & 1;
    __syncthreads();   // drains vmcnt(0): stage(it) landed; trig(it) visible

    if (it + 1 < 16) {
      STG(it + 1, b ^ 1);
      if (t < 32) {
        const float ang = PI2_ * (float)(kseg * 512 + (it + 1) * 32 + t + 1) / (float)L_;
        snl[(it + 1) & 1][t] = __sinf(ang); csl[(it + 1) & 1][t] = __cosf(ang);
      }
    }

    // build Bsn/Bcs from vt[b] (each thread: one bf16x8 chunk)
    {
      const int row = t >> 2, cc = (t & 3) * 8;
      bf16x8 v = *(const bf16x8*)&vt[b][row * 32 + cc];
      bf16x8 a, c;
#pragma unroll
      for (int e = 0; e < 8; e++) {
        const float f = (float)v[e];
        a[e] = (bf16)(f * snl[b][cc + e]);
        c[e] = (bf16)(f * csl[b][cc + e]);
      }
      *(bf16x8*)&Bsn[row * 40 + cc] = a;
      *(bf16x8*)&Bcs[row * 40 + cc] = c;
    }
    // rowsums (ks partials) from swizzled ktb[b]
    if (t < 128) {
      float r8 = 0.f;
#pragma unroll
      for (int p = 0; p < 4; p++) {
        bf16x8 v = *(const bf16x8*)&ktb[b][d_ * 32 + p * 8];
        const int gl = (p ^ (d_ & 1)) * 8;
#pragma unroll
        for (int e = 0; e < 8; e++)
          r8 += (float)v[e] * (h_ ? csl[b][gl + e] : snl[b][gl + e]);
      }
      rs += r8;
    }
    LGKM0(); BAR();    // ds_writes visible; staged cp16s stay in flight

    bf16x8 af[4], bfm[2];
    const bf16* Bsel = wm ? Bcs : Bsn;
#pragma unroll
    for (int i = 0; i < 4; i++)
      af[i] = *(const bf16x8*)&ktb[b][(i * 16 + l15) * 32 + ((quad ^ (l15 & 1)) * 8)];
#pragma unroll
    for (int j = 0; j < 2; j++)
      bfm[j] = *(const bf16x8*)&Bsel[(wn * 32 + j * 16 + l15) * 40 + quad * 8];
#pragma unroll
    for (int i = 0; i < 4; i++)
#pragma unroll
      for (int j = 0; j < 2; j++)
        acc[i][j] = __builtin_amdgcn_mfma_f32_16x16x32_bf16(af[i], bfm[j], acc[i][j], 0, 0, 0);
  }

  float* C = kvp + (size_t)(kseg * 128 + bh) * 128 * 68;
#pragma unroll
  for (int i = 0; i < 4; i++)
#pragma unroll
    for (int j = 0; j < 2; j++) {
      const int col = wn * 32 + j * 16 + l15;
#pragma unroll
      for (int r = 0; r < 4; r++) {
        const int row = wm * 64 + i * 16 + quad * 4 + r;
        C[(size_t)row * 68 + col] = acc[i][j][r];
      }
    }
  if (t < 128) C[(size_t)t * 68 + 64] = rs;
}

// ---------------------------------------------------------------------------
// K5: consts (256 threads: 4-way f-chunk parallelism + LDS reduce).
// ---------------------------------------------------------------------------
__global__ __launch_bounds__(256) void k_consts(const float* __restrict__ kvp,
                                                bf16* __restrict__ KVT,
                                                float* __restrict__ ksbuf) {
  __shared__ float red[4][64];
  __shared__ float sksh[2];
  const int bh = blockIdx.x;
  const int t  = threadIdx.x;
  const int fq = t >> 6, dp = t & 63;
  const size_t gs = (size_t)128 * 128 * 68;
  const float* P = kvp + (size_t)bh * 128 * 68;
  bf16* kr = KVT + (size_t)(bh * 64 + dp) * 160;
  float sp = 0.f;
#pragma unroll 8
  for (int f = fq * 32; f < fq * 32 + 32; f++) {
    float v = P[(size_t)f * 68 + dp] + P[gs + (size_t)f * 68 + dp]
            + P[2 * gs + (size_t)f * 68 + dp] + P[3 * gs + (size_t)f * 68 + dp];
    kr[f] = (bf16)v;
    sp += v;
  }
  red[fq][dp] = sp;
  float ksv = 0.f;
  if (t < 128) {
    ksv = P[(size_t)t * 68 + 64] + P[gs + (size_t)t * 68 + 64]
        + P[2 * gs + (size_t)t * 68 + 64] + P[3 * gs + (size_t)t * 68 + 64];
    ksbuf[(size_t)bh * 136 + t] = ksv;
  }
  float sks = ksv;
#pragma unroll
  for (int o = 1; o < 64; o <<= 1) sks += __shfl_xor(sks, o);
  if (t == 0)  sksh[0] = sks;   // sum of ks0 (wave 0)
  if (t == 64) sksh[1] = sks;   // sum of ks1 (wave 1)
  __syncthreads();
  if (t < 64) {
    const float sk0 = red[0][t] + red[1][t];
    const float sk1 = red[2][t] + red[3][t];
    kr[128] = (bf16)(62.f * sk0);
    kr[129] = (bf16)(62.f * sk1);
#pragma unroll
    for (int f = 130; f < 160; f++) kr[f] = (bf16)0.f;
    if (t == 0) {
      ksbuf[(size_t)bh * 136 + 128] = sksh[0];
      ksbuf[(size_t)bh * 136 + 129] = sksh[1];
    }
  }
}

// ---------------------------------------------------------------------------
// K6: fused attention.  Cooperative vectorized q-tile load into LDS (reuses
// the Abuf region; 8x fewer VMEM insts than per-thread scalar loads), then
// column reads.  Output repacked through LDS (stride-72) with normal
// full-line stores (attnb is re-read by the final GEMM).
// ---------------------------------------------------------------------------
#define ASTR 168
#define OSTR 72
#define QSTR 136
__global__ __launch_bounds__(256) void k_attn(const bf16* __restrict__ QTb,
                                              const bf16* __restrict__ KVT,
                                              const float* __restrict__ ksbuf,
                                              bf16* __restrict__ attn) {
  __shared__ __attribute__((aligned(16))) bf16 Abuf[128 * ASTR];
  __shared__ __attribute__((aligned(16))) bf16 Bbuf[64 * ASTR];
  __shared__ float ksl[136];
  __shared__ float pth0[2][128], pth1[2][128];
  const int lc = blockIdx.x;   // 0..15
  const int bh = blockIdx.y;
  const int b = bh >> 4, h = bh & 15;
  const int t = threadIdx.x;

  // q-tile staging area overlaps Abuf (freed before Abuf is written):
  // qld[d][l'] with stride 136 (16B-aligned rows, <=2-way banks on col reads)
  bf16* qld = Abuf;   // uses 64*136 = 8704 of Abuf's 21504 elements

  {
    const bf16* src = KVT + (size_t)bh * 64 * 160;
#pragma unroll
    for (int i = 0; i < 5; i++) {
      const int idx = t + i * 256;
      const int row = idx / 20, ch = idx % 20;
      *(bf16x8*)&Bbuf[row * ASTR + ch * 8] = *(const bf16x8*)(src + row * 160 + ch * 8);
    }
    // cooperative q-tile load: 64 d-rows x 128 l's as bf16x8 chunks
    const bf16* qsrc = QTb + (size_t)bh * 64 * 2048 + lc * 128;
#pragma unroll
    for (int i = 0; i < 4; i++) {
      const int idx = t + i * 256;          // 0..1023
      const int d = idx >> 4, cc = (idx & 15) * 8;
      uintx4 v = __builtin_nontemporal_load(
          reinterpret_cast<const uintx4*>(qsrc + (size_t)d * 2048 + cc));
      *(uintx4*)&qld[d * QSTR + cc] = v;
    }
    if (t < 130) ksl[t] = ksbuf[(size_t)bh * 136 + t];
  }
  __syncthreads();

  const int lr = t & 127, hf = t >> 7;
  const int l  = lc * 128 + lr;
  float xv[32];
  {
#pragma unroll
    for (int d = 0; d < 32; d++) xv[d] = (float)qld[(hf * 32 + d) * QSTR + lr];
    float pa = 0.f, pb = 0.f;
#pragma unroll
    for (int d = 0; d < 32; d++) {
      pa += xv[d] * ksl[hf * 32 + d];
      pb += xv[d] * ksl[64 + hf * 32 + d];
    }
    pth0[hf][lr] = pa; pth1[hf][lr] = pb;
  }
  __syncthreads();   // pth visible AND all qld reads done (Abuf overwrite ok)

  {
    const float t0 = pth0[0][lr] + pth0[1][lr];
    const float t1 = pth1[0][lr] + pth1[1][lr];
    const float SKS0 = ksl[128], SKS1 = ksl[129];
    const float ang = PI2_ * (float)(l + 1) / (float)L_;
    const float sn = __sinf(ang), cs = __cosf(ang);
    const float den1 = sn * t0 + cs * t1;
    const float den2 = sn * (62.f * SKS0 + t0) + cs * (62.f * SKS1 + t1);
    const float z1 = 1.f / fmaxf(den1, EPS_);
    const float z2 = 1.f / fmaxf(den2, EPS_);
    const float zz = z1 + z2;
    const float a0 = zz * sn, a1 = zz * cs;
    bf16* ar = &Abuf[lr * ASTR];
#pragma unroll
    for (int g = 0; g < 4; g++) {
      bf16x8 w;
#pragma unroll
      for (int j = 0; j < 8; j++) w[j] = (bf16)(a0 * xv[g * 8 + j]);
      *(bf16x8*)(ar + hf * 32 + g * 8) = w;
    }
#pragma unroll
    for (int g = 0; g < 4; g++) {
      bf16x8 w;
#pragma unroll
      for (int j = 0; j < 8; j++) w[j] = (bf16)(a1 * xv[g * 8 + j]);
      *(bf16x8*)(ar + 64 + hf * 32 + g * 8) = w;
    }
    if (hf) {
      bf16x8 wt = {};
      wt[0] = (bf16)(z2 * sn); wt[1] = (bf16)(z2 * cs);
      *(bf16x8*)(ar + 128) = wt;
      bf16x8 zr = {};
      *(bf16x8*)(ar + 136) = zr;
      *(bf16x8*)(ar + 144) = zr;
      *(bf16x8*)(ar + 152) = zr;
    }
  }
  __syncthreads();

  const int wid = t >> 6, lane = t & 63;
  const int quad = lane >> 4, l15 = lane & 15;
  const int wm = wid >> 1, wn = wid & 1;
  floatx4 acc[4][2] = {};
#pragma unroll
  for (int kk = 0; kk < 5; kk++) {
    bf16x8 af[4], bfm[2];
#pragma unroll
    for (int i = 0; i < 4; i++)
      af[i] = *(const bf16x8*)&Abuf[(wm * 64 + i * 16 + l15) * ASTR + kk * 32 + quad * 8];
#pragma unroll
    for (int j = 0; j < 2; j++)
      bfm[j] = *(const bf16x8*)&Bbuf[(wn * 32 + j * 16 + l15) * ASTR + kk * 32 + quad * 8];
#pragma unroll
    for (int i = 0; i < 4; i++)
#pragma unroll
      for (int j = 0; j < 2; j++)
        acc[i][j] = __builtin_amdgcn_mfma_f32_16x16x32_bf16(af[i], bfm[j], acc[i][j], 0, 0, 0);
  }

  // ---- out repack: [l local][64] bf16, stride 72; then full-line burst ----
  __syncthreads();   // all Abuf MFMA reads done
  bf16* ob = Abuf;
#pragma unroll
  for (int i = 0; i < 4; i++)
#pragma unroll
    for (int j = 0; j < 2; j++) {
      const int dp = wn * 32 + j * 16 + l15;
#pragma unroll
      for (int r = 0; r < 4; r++) {
        const int ll = wm * 64 + i * 16 + quad * 4 + r;
        ob[ll * OSTR + dp] = (bf16)acc[i][j][r];
      }
    }
  __syncthreads();
  {
    const int ll = t >> 1, half = t & 1;
    const size_t gbase = ((size_t)(lc * 128 + ll) * B_ + b) * E_ + h * 64 + half * 32;
#pragma unroll
    for (int g = 0; g < 4; g++) {
      bf16x8 v = *(const bf16x8*)&ob[ll * OSTR + half * 32 + g * 8];
      *(bf16x8*)&attn[gbase + g * 8] = v;
    }
  }
}

// ---------------------------------------------------------------------------
// Workspace layout (bytes), total 163,123,200 (<= 243,269,632):
//  QTb   bf16 [128][64][2048]  @ 0             (33,554,432)
//  KTb   bf16 [128][64][2048]  @  33,554,432   (33,554,432)
//  VT    bf16 [128][64][2048]  @  67,108,864   (33,554,432)
//  Wt    bf16 x4               @ 100,663,296   ( 8,388,608)
//  Xbf   bf16                  @ 109,051,904   (33,554,432) -> attnb overlay
//  kvp   fp32 [4][128][128][68]@ 142,606,336   (17,825,792)
//  KVT   bf16 [128][64][160]   @ 160,432,128   ( 2,621,440)
//  ksbuf fp32 [128][136]       @ 163,053,568   (    69,632)
// ---------------------------------------------------------------------------
extern "C" void kernel_launch(void* const* d_in, const int* in_sizes, int n_in,
                              void* d_out, int out_size, void* d_ws, size_t ws_size,
                              hipStream_t stream) {
  (void)in_sizes; (void)n_in; (void)out_size; (void)ws_size;
  const float* query = (const float*)d_in[0];
  const float* Wq = (const float*)d_in[1];
  const float* bq = (const float*)d_in[2];
  const float* Wk = (const float*)d_in[3];
  const float* bk = (const float*)d_in[4];
  const float* Wv = (const float*)d_in[5];
  const float* bv = (const float*)d_in[6];
  const float* Wo = (const float*)d_in[7];
  const float* bo = (const float*)d_in[8];

  char* ws = (char*)d_ws;
  bf16*  QTb  = (bf16*) (ws + 0);
  bf16*  KTb  = (bf16*) (ws + 33554432);
  bf16*  VT   = (bf16*) (ws + 67108864);
  bf16*  Wt   = (bf16*) (ws + 100663296);
  bf16*  Xbf  = (bf16*) (ws + 109051904);
  bf16*  attnb= (bf16*) (ws + 109051904);
  float* kvp  = (float*)(ws + 142606336);
  bf16*  KVT  = (bf16*) (ws + 160432128);
  float* ksbuf= (float*)(ws + 163053568);

  // 1) X -> bf16
  k_convert_x<<<(M_ * E_) / (256 * 8), 256, 0, stream>>>(query, Xbf);

  // 2) W^T -> bf16 for all four weights
  TArgs ta;
  ta.src[0] = Wq; ta.src[1] = Wk; ta.src[2] = Wv; ta.src[3] = Wo;
  ta.dst[0] = Wt;                       ta.dst[1] = Wt + (size_t)E_ * E_;
  ta.dst[2] = Wt + (size_t)2 * E_ * E_; ta.dst[3] = Wt + (size_t)3 * E_ * E_;
  k_transpose_w<<<dim3(32, 32, 4), dim3(32, 8), 0, stream>>>(ta);

  // 3) QKV GEMM + fused q/k-softmax (normal full-line stores, bm-inner grid)
  k_gemm_qkv256<<<768, 512, 0, stream>>>(Xbf, Wt, bq, bk, bv, QTb, KTb, VT);

  // 4) KV GEMM from bf16 probs (2-barrier double-buffered)
  k_kv<<<dim3(4, 128), 256, 0, stream>>>(KTb, VT, kvp);

  // 5) consts: KVT + ksbuf
  k_consts<<<128, 256, 0, stream>>>(kvp, KVT, ksbuf);

  // 6) fused attention
  k_attn<<<dim3(16, 128), 256, 0, stream>>>(QTb, KVT, ksbuf, attnb);

  // 7) final projection -> d_out
  k_gemm_final256<<<256, 512, 0, stream>>>(attnb, Wt + (size_t)3 * E_ * E_, bo, (float*)d_out);
}